// Round 4
// baseline (386.755 us; speedup 1.0000x reference)
//
#include <hip/hip_runtime.h>
#include <hip/hip_bf16.h>
#include <cfloat>
#include <math.h>

// Problem constants
#define S_LEN 1024
#define DIM 512
#define H_N 8
#define DH 64
#define CB 32
#define NB 32
#define NSEL 4
#define NMEM 4
#define WIN 64
#define SCALE 0.125f
#define EPS 1.1920929e-07f

// ---------------- ws layout (float offsets) ----------------
#define OFF_X      0u
#define OFF_QKV    524288u     // 1024*1536
#define OFF_RQ     2097152u
#define OFF_RK     2621440u
#define OFF_COS    3145728u
#define OFF_SIN    3178496u
#define OFF_TK     3211264u
#define OFF_TV     3735552u
#define OFF_HK     4259840u
#define OFF_HV     4784128u
#define OFF_CKC    5308416u    // 256*64
#define OFF_CVC    5324800u
#define OFF_STRAT  5341184u    // 1024*24
#define OFF_ATT    5365760u    // 1024*512
#define OFF_QKVP   2097152u    // 2 x 1024*1536 partials (overlap RQ..HV)
#define OFF_COMPP  5890048u    // 8 x 256*2048 partials
#define OFF_OUTP   5890048u    // 4 x 1024*512 partials (reuse COMPP)

// ---------------- RMSNorm + strategy gates (fused) ----------------
__global__ void rmsnorm_strat_k(const float* __restrict__ inp, const float* __restrict__ g,
                                const float* __restrict__ sw, const float* __restrict__ sb,
                                float* __restrict__ x, float* __restrict__ strat) {
    int s = blockIdx.x;
    int t = threadIdx.x;
    __shared__ __align__(16) float xs[512];
    __shared__ float red[24][8];
    float v0 = inp[s * DIM + t];
    float v1 = inp[s * DIM + t + 256];
    float ss = v0 * v0 + v1 * v1;
    for (int o = 32; o > 0; o >>= 1) ss += __shfl_xor(ss, o);
    __shared__ float wsum[4];
    int wid = t >> 6, lane = t & 63;
    if (lane == 0) wsum[wid] = ss;
    __syncthreads();
    float tot = wsum[0] + wsum[1] + wsum[2] + wsum[3];
    float scale = 1.0f / sqrtf(tot / (float)DIM + EPS);
    float x0 = v0 * scale * g[t];
    float x1 = v1 * scale * g[t + 256];
    x[s * DIM + t]       = x0;
    x[s * DIM + t + 256] = x1;
    xs[t] = x0;
    xs[t + 256] = x1;
    __syncthreads();
    if (t < 192) {
        int o = t >> 3, p = t & 7;
        float acc = 0.0f;
        const float* xb = xs + p * 64;
        for (int k = 0; k < 64; ++k) acc += xb[k] * sw[(p * 64 + k) * 24 + o];
        red[o][p] = acc;
    }
    __syncthreads();
    if (t < 24) {
        float a = sb[t];
        for (int p = 0; p < 8; ++p) a += red[t][p];
        strat[s * 24 + t] = 1.0f / (1.0f + expf(-a));
    }
}

// ---------------- RoPE cos/sin table ----------------
__global__ void rope_table_k(float* __restrict__ cost, float* __restrict__ sint) {
    int idx = blockIdx.x * 256 + threadIdx.x;   // 1024*32
    int s = idx >> 5, i = idx & 31;
    double inv = pow(10000.0, -(double)(2 * i) / 64.0);
    double ang = (double)s * inv;
    cost[idx] = (float)cos(ang);
    sint[idx] = (float)sin(ang);
}

// ---------------- RoPE apply to q,k ----------------
__global__ void rope_apply_k(const float* __restrict__ qkv, const float* __restrict__ cost,
                             const float* __restrict__ sint,
                             float* __restrict__ rq, float* __restrict__ rk) {
    int idx = blockIdx.x * 256 + threadIdx.x;   // 1024*8*32 pairs
    int s = idx >> 8;
    int rem = idx & 255;
    int h = rem >> 5, i = rem & 31;
    float c = cost[s * 32 + i], sn = sint[s * 32 + i];
    int qb = s * 1536 + h * 64 + 2 * i;
    float q0 = qkv[qb], q1 = qkv[qb + 1];
    int ob = s * 512 + h * 64 + 2 * i;
    rq[ob]     = q0 * c - q1 * sn;
    rq[ob + 1] = q1 * c + q0 * sn;
    float k0 = qkv[qb + 512], k1 = qkv[qb + 513];
    rk[ob]     = k0 * c - k1 * sn;
    rk[ob + 1] = k1 * c + k0 * sn;
}

// ---------------- build compress-MLP inputs ----------------
__global__ void tkv_k(const float* __restrict__ qkv, const float* __restrict__ k_pos,
                      const float* __restrict__ v_pos,
                      float* __restrict__ tk, float* __restrict__ tv) {
    int idx = blockIdx.x * 256 + threadIdx.x;   // 256*2048
    int row = idx >> 11;
    int c = idx & 2047;
    int h = row >> 5, nb = row & 31;
    int cb = c >> 6, d = c & 63;
    int srow = nb * 32 + cb;
    tk[idx] = qkv[srow * 1536 + 512 + h * 64 + d] + k_pos[(h * 32 + cb) * 64 + d];
    tv[idx] = qkv[srow * 1536 + 1024 + h * 64 + d] + v_pos[(h * 32 + cb) * 64 + d];
}

// ---------------- f32 GEMM 64x64 tile, split-K partial writer ----------------
__device__ __forceinline__ void gemm_sk_body(const float* __restrict__ A, const float* __restrict__ B,
                                             float* __restrict__ P, int M, int N, int K,
                                             int kstart, int Ks) {
    __shared__ __align__(16) float As[2][16][68];
    __shared__ __align__(16) float Bs[2][16][64];
    const int bm = blockIdx.x * 64, bn = blockIdx.y * 64;
    const int tid = threadIdx.x;
    const int tx = tid & 15, ty = tid >> 4;
    const int ar = tid >> 2;
    const int ac = (tid & 3) * 4;
    const int br = tid >> 4;
    const int bc = (tid & 15) * 4;
    const float* Aptr = A + (size_t)(bm + ar) * K + kstart + ac;
    const float* Bptr = B + (size_t)(kstart + br) * N + bn + bc;

    float4 a4 = *(const float4*)(Aptr);
    float4 b4 = *(const float4*)(Bptr);
    float acc[4][4] = {};
    int buf = 0;
    for (int k0 = 0; k0 < Ks; k0 += 16) {
        As[buf][ac + 0][ar] = a4.x;
        As[buf][ac + 1][ar] = a4.y;
        As[buf][ac + 2][ar] = a4.z;
        As[buf][ac + 3][ar] = a4.w;
        *(float4*)&Bs[buf][br][bc] = b4;
        __syncthreads();
        if (k0 + 16 < Ks) {
            a4 = *(const float4*)(Aptr + k0 + 16);
            b4 = *(const float4*)(Bptr + (size_t)(k0 + 16) * N);
        }
#pragma unroll
        for (int kk = 0; kk < 16; ++kk) {
            const float4 af = *(const float4*)&As[buf][kk][ty * 4];
            const float4 bf = *(const float4*)&Bs[buf][kk][tx * 4];
            acc[0][0] += af.x * bf.x; acc[0][1] += af.x * bf.y; acc[0][2] += af.x * bf.z; acc[0][3] += af.x * bf.w;
            acc[1][0] += af.y * bf.x; acc[1][1] += af.y * bf.y; acc[1][2] += af.y * bf.z; acc[1][3] += af.y * bf.w;
            acc[2][0] += af.z * bf.x; acc[2][1] += af.z * bf.y; acc[2][2] += af.z * bf.z; acc[2][3] += af.z * bf.w;
            acc[3][0] += af.w * bf.x; acc[3][1] += af.w * bf.y; acc[3][2] += af.w * bf.z; acc[3][3] += af.w * bf.w;
        }
        buf ^= 1;
    }
#pragma unroll
    for (int i = 0; i < 4; ++i) {
        int m = bm + ty * 4 + i;
        float4 v;
        v.x = acc[i][0]; v.y = acc[i][1]; v.z = acc[i][2]; v.w = acc[i][3];
        *(float4*)&P[(size_t)m * N + bn + tx * 4] = v;
    }
}

__global__ void gemm_sk_k(const float* __restrict__ A, const float* __restrict__ B,
                          float* __restrict__ P, int M, int N, int K, int nsplit) {
    int kz = blockIdx.z;
    int Ks = K / nsplit;
    gemm_sk_body(A, B, P + (size_t)kz * M * N, M, N, K, kz * Ks, Ks);
}

__global__ void gemm_comp_k(const float* __restrict__ A0, const float* __restrict__ B0,
                            const float* __restrict__ A1, const float* __restrict__ B1,
                            float* __restrict__ P, int M, int N, int K) {
    int z = blockIdx.z;
    int g = z >> 2, kz = z & 3;
    const float* A = g ? A1 : A0;
    const float* B = g ? B1 : B0;
    int Ks = K >> 2;
    gemm_sk_body(A, B, P + (size_t)z * M * N, M, N, K, kz * Ks, Ks);
}

// ---------------- split-K reduce (+bias,+relu) ----------------
template <int NS, bool RELU, bool BIAS>
__global__ void reduce_k(const float* __restrict__ P, const float* __restrict__ bias,
                         float* __restrict__ Y, int MN, int N) {
    int idx4 = blockIdx.x * 256 + threadIdx.x;
    if (idx4 * 4 >= MN) return;
    const float4* p4 = (const float4*)P;
    int mn4 = MN >> 2;
    float4 v = p4[idx4];
#pragma unroll
    for (int j = 1; j < NS; ++j) {
        float4 w = p4[idx4 + j * (size_t)mn4];
        v.x += w.x; v.y += w.y; v.z += w.z; v.w += w.w;
    }
    if (BIAS) {
        int col = (idx4 * 4) % N;
        float4 b = *(const float4*)(bias + col);
        v.x += b.x; v.y += b.y; v.z += b.z; v.w += b.w;
    }
    if (RELU) {
        v.x = fmaxf(v.x, 0.f); v.y = fmaxf(v.y, 0.f);
        v.z = fmaxf(v.z, 0.f); v.w = fmaxf(v.w, 0.f);
    }
    ((float4*)Y)[idx4] = v;
}

// ---------------- skinny GEMM: C(Mx64) = A(MxK) @ B(Kx64) + bias ----------------
__device__ __forceinline__ void skinny_body(const float* __restrict__ A, const float* __restrict__ B,
                                            const float* __restrict__ bias, float* __restrict__ C, int K) {
    int row = blockIdx.x;
    int col = threadIdx.x & 63;
    int chunk = threadIdx.x >> 6;
    int kpc = K >> 2;
    const float* a = A + (size_t)row * K + chunk * kpc;
    const float* b = B + (size_t)chunk * kpc * 64;
    float acc = 0.0f;
    for (int k = 0; k < kpc; k += 4) {
        float4 av = *(const float4*)(a + k);
        acc += av.x * b[(k + 0) * 64 + col];
        acc += av.y * b[(k + 1) * 64 + col];
        acc += av.z * b[(k + 2) * 64 + col];
        acc += av.w * b[(k + 3) * 64 + col];
    }
    __shared__ float red[4][64];
    red[chunk][col] = acc;
    __syncthreads();
    if (chunk == 0)
        C[(size_t)row * 64 + col] = red[0][col] + red[1][col] + red[2][col] + red[3][col] + bias[col];
}

__global__ void gemm_skinny_z2_k(const float* __restrict__ A0, const float* __restrict__ B0,
                                 const float* __restrict__ b0, float* __restrict__ C0,
                                 const float* __restrict__ A1, const float* __restrict__ B1,
                                 const float* __restrict__ b1, float* __restrict__ C1, int K) {
    if (blockIdx.z == 0) skinny_body(A0, B0, b0, C0, K);
    else                 skinny_body(A1, B1, b1, C1, K);
}

// ---------------- helpers for fused attention ----------------
// 4-accumulator dot: chain depth ~4 instead of 64
__device__ __forceinline__ float dot64i(const float* __restrict__ qsh, const float* __restrict__ kr) {
    const float4* q4 = (const float4*)qsh;
    const float4* k4 = (const float4*)kr;
    float a0 = 0, a1 = 0, a2 = 0, a3 = 0;
#pragma unroll
    for (int i = 0; i < 16; i += 4) {
        float4 qa = q4[i],     ka = k4[i];
        float4 qb = q4[i + 1], kb = k4[i + 1];
        float4 qc = q4[i + 2], kc = k4[i + 2];
        float4 qd = q4[i + 3], kd = k4[i + 3];
        a0 += (qa.x * ka.x + qa.y * ka.y) + (qa.z * ka.z + qa.w * ka.w);
        a1 += (qb.x * kb.x + qb.y * kb.y) + (qb.z * kb.z + qb.w * kb.w);
        a2 += (qc.x * kc.x + qc.y * kc.y) + (qc.z * kc.z + qc.w * kc.w);
        a3 += (qd.x * kd.x + qd.y * kd.y) + (qd.z * kd.z + qd.w * kd.w);
    }
    return (a0 + a1) + (a2 + a3);
}

__device__ __forceinline__ float redmax64(float v) {
    for (int o = 32; o > 0; o >>= 1) v = fmaxf(v, __shfl_xor(v, o));
    return v;
}
__device__ __forceinline__ float redsum64(float v) {
    for (int o = 32; o > 0; o >>= 1) v += __shfl_xor(v, o);
    return v;
}

// ---------------- fused attention: comp + topk + fine + slide + gates ----------------
// 256-thread blocks; wave w handles s = blockIdx.x*4 + w, head = blockIdx.y
__global__ __launch_bounds__(256) void attn_fused_k(
    const float* __restrict__ qkv, const float* __restrict__ rq,
    const float* __restrict__ rk, const float* __restrict__ ckc,
    const float* __restrict__ cvc, const float* __restrict__ mem_kv,
    const float* __restrict__ strat, float* __restrict__ att) {
    int w = threadIdx.x >> 6, lane = threadIdx.x & 63;
    int s = blockIdx.x * 4 + w, h = blockIdx.y;
    __shared__ __align__(16) float qs[4][64];
    __shared__ __align__(16) float rqs[4][64];
    __shared__ float pa[4][192];
    __shared__ int rows[4][192];
    float* qsw  = qs[w];
    float* rqsw = rqs[w];
    float* paw  = pa[w];
    int*   rww  = rows[w];
    qsw[lane]  = qkv[s * 1536 + h * 64 + lane];
    rqsw[lane] = rq[s * 512 + h * 64 + lane];
    __syncthreads();

    // ---- compressed attention (36 keys) ----
    float sim = -FLT_MAX;
    if (lane < 36) {
        bool valid = (lane < NMEM) || ((lane - NMEM + 1) * CB - 1 < s);
        if (valid) {
            const float* kr = (lane < NMEM) ? (mem_kv + (h * 4 + lane) * 64)
                                            : (ckc + (h * 32 + lane - NMEM) * 64);
            sim = dot64i(qsw, kr) * SCALE;
        }
    }
    float mx = redmax64(sim);
    float e = (sim == -FLT_MAX) ? 0.0f : expf(sim - mx);
    float tot = redsum64(e);
    float a = e / tot;
    paw[lane] = (lane < 36) ? a : 0.0f;
    __syncthreads();
    // comp PV: 4 mem slots + 32 comp blocks, 4 accumulators, zero-group skip
    float c0, c1, c2, c3;
    {
        const float* mv = mem_kv + 2048 + h * 256 + lane;
        c0 = paw[0] * mv[0];
        c1 = paw[1] * mv[64];
        c2 = paw[2] * mv[128];
        c3 = paw[3] * mv[192];
        const float* cvb = cvc + h * 2048 + lane;
#pragma unroll 1
        for (int j = 0; j < 32; j += 4) {
            float w0 = paw[4 + j], w1 = paw[5 + j], w2 = paw[6 + j], w3 = paw[7 + j];
            if (w0 + w1 + w2 + w3 != 0.0f) {
                c0 += w0 * cvb[(j + 0) * 64];
                c1 += w1 * cvb[(j + 1) * 64];
                c2 += w2 * cvb[(j + 2) * 64];
                c3 += w3 * cvb[(j + 3) * 64];
            }
        }
    }
    float c_acc = (c0 + c1) + (c2 + c3);

    // ---- top-4 (wave-parallel, lowest-index tie-break) ----
    float tval = (lane >= NMEM && lane < 36) ? a : -1.0f;
    int tidx = lane - NMEM;
    int sel0, sel1, sel2, sel3, msk = 0;
#pragma unroll
    for (int t = 0; t < NSEL; ++t) {
        float bv = tval; int bi = tidx;
        for (int o = 32; o > 0; o >>= 1) {
            float ov = __shfl_xor(bv, o);
            int oi = __shfl_xor(bi, o);
            if (ov > bv || (ov == bv && oi < bi)) { bv = ov; bi = oi; }
        }
        if (t == 0) sel0 = bi; else if (t == 1) sel1 = bi;
        else if (t == 2) sel2 = bi; else sel3 = bi;
        if (bv > 1e-10f) msk |= 1 << t;
        if (tidx == bi && lane >= NMEM && lane < 36) tval = -1.0f;
    }

    // ---- fine attention over 160 keys ----
    int own = s >> 5, p = s & 31, t31 = lane & 31;
    bool hi = lane >= 32;
    int blkA = hi ? sel1 : sel0;
    bool valA = hi ? (msk & 2) : (msk & 1);
    int rowA = blkA * 32 + t31;
    float simA = valA ? dot64i(rqsw, rk + rowA * 512 + h * 64) * SCALE : -FLT_MAX;
    int blkB = hi ? sel3 : sel2;
    bool valB = hi ? (msk & 8) : (msk & 4);
    int rowB = blkB * 32 + t31;
    float simB = valB ? dot64i(rqsw, rk + rowB * 512 + h * 64) * SCALE : -FLT_MAX;
    int rowC = own * 32 + t31;
    bool valC = (!hi) && (t31 <= p);
    float simC = valC ? dot64i(rqsw, rk + rowC * 512 + h * 64) * SCALE : -FLT_MAX;

    float fmx = redmax64(fmaxf(fmaxf(simA, simB), simC));
    float eA = (simA == -FLT_MAX) ? 0.0f : expf(simA - fmx);
    float eB = (simB == -FLT_MAX) ? 0.0f : expf(simB - fmx);
    float eC = (simC == -FLT_MAX) ? 0.0f : expf(simC - fmx);
    float fsum = redsum64(eA + eB + eC);
    float finv = 1.0f / fsum;
    paw[lane] = eA * finv;        rww[lane] = rowA;
    paw[64 + lane] = eB * finv;   rww[64 + lane] = rowB;
    paw[128 + lane] = eC * finv;  rww[128 + lane] = rowC;
    __syncthreads();
    const float* vb = qkv + 1024 + h * 64 + lane;
    float f0 = 0, f1 = 0, f2 = 0, f3 = 0;
#pragma unroll 1
    for (int kk = 0; kk < 160; kk += 4) {
        float w0 = paw[kk], w1 = paw[kk + 1], w2 = paw[kk + 2], w3 = paw[kk + 3];
        if (w0 + w1 + w2 + w3 != 0.0f) {
            f0 += w0 * vb[(size_t)rww[kk] * 1536];
            f1 += w1 * vb[(size_t)rww[kk + 1] * 1536];
            f2 += w2 * vb[(size_t)rww[kk + 2] * 1536];
            f3 += w3 * vb[(size_t)rww[kk + 3] * 1536];
        }
    }
    float f_acc = (f0 + f1) + (f2 + f3);
    __syncthreads();

    // ---- sliding-window attention ----
    int lo = (s > WIN) ? s - WIN : 0;
    int cnt = s - lo + 1;   // <= 65
    float sA = (lane < cnt) ? dot64i(rqsw, rk + (lo + lane) * 512 + h * 64) * SCALE : -FLT_MAX;
    float sB = (64 + lane < cnt) ? dot64i(rqsw, rk + (lo + 64 + lane) * 512 + h * 64) * SCALE : -FLT_MAX;
    float smx = redmax64(fmaxf(sA, sB));
    float esA = (sA == -FLT_MAX) ? 0.0f : expf(sA - smx);
    float esB = (sB == -FLT_MAX) ? 0.0f : expf(sB - smx);
    float ssum = redsum64(esA + esB);
    float sinv = 1.0f / ssum;
    paw[lane] = esA * sinv;
    if (64 + lane < cnt) paw[64 + lane] = esB * sinv;
    __syncthreads();
    float s0 = 0, s1 = 0, s2 = 0, s3 = 0;
    const float* vlo = vb + (size_t)lo * 1536;
    int kk = 0;
#pragma unroll 1
    for (; kk + 4 <= cnt; kk += 4) {
        s0 += paw[kk] * vlo[(size_t)kk * 1536];
        s1 += paw[kk + 1] * vlo[(size_t)(kk + 1) * 1536];
        s2 += paw[kk + 2] * vlo[(size_t)(kk + 2) * 1536];
        s3 += paw[kk + 3] * vlo[(size_t)(kk + 3) * 1536];
    }
    for (; kk < cnt; ++kk) s0 += paw[kk] * vlo[(size_t)kk * 1536];
    float s_acc = (s0 + s1) + (s2 + s3);

    // ---- gated combine ----
    const float* st = strat + s * 24 + h * 3;
    att[s * 512 + h * 64 + lane] = st[0] * c_acc + st[1] * f_acc + st[2] * s_acc;
}

extern "C" void kernel_launch(void* const* d_in, const int* in_sizes, int n_in,
                              void* d_out, int out_size, void* d_ws, size_t ws_size,
                              hipStream_t stream) {
    const float* inp     = (const float*)d_in[0];
    const float* norm_g  = (const float*)d_in[1];
    const float* w_qkv   = (const float*)d_in[2];
    const float* k_pos   = (const float*)d_in[3];
    const float* v_pos   = (const float*)d_in[4];
    const float* kc_w1   = (const float*)d_in[5];
    const float* kc_b1   = (const float*)d_in[6];
    const float* kc_w2   = (const float*)d_in[7];
    const float* kc_b2   = (const float*)d_in[8];
    const float* vc_w1   = (const float*)d_in[9];
    const float* vc_b1   = (const float*)d_in[10];
    const float* vc_w2   = (const float*)d_in[11];
    const float* vc_b2   = (const float*)d_in[12];
    const float* mem_kv  = (const float*)d_in[13];
    const float* strat_w = (const float*)d_in[14];
    const float* strat_b = (const float*)d_in[15];
    const float* out_w   = (const float*)d_in[16];
    float* out = (float*)d_out;

    float* ws = (float*)d_ws;
    float* x     = ws + OFF_X;
    float* qkv   = ws + OFF_QKV;
    float* rq    = ws + OFF_RQ;
    float* rk    = ws + OFF_RK;
    float* cost  = ws + OFF_COS;
    float* sint  = ws + OFF_SIN;
    float* tk    = ws + OFF_TK;
    float* tv    = ws + OFF_TV;
    float* hk    = ws + OFF_HK;
    float* hv    = ws + OFF_HV;
    float* ckc   = ws + OFF_CKC;
    float* cvc   = ws + OFF_CVC;
    float* strat = ws + OFF_STRAT;
    float* att   = ws + OFF_ATT;
    float* qkvp  = ws + OFF_QKVP;
    float* compp = ws + OFF_COMPP;
    float* outp  = ws + OFF_OUTP;

    rmsnorm_strat_k<<<1024, 256, 0, stream>>>(inp, norm_g, strat_w, strat_b, x, strat);
    gemm_sk_k<<<dim3(16, 24, 2), 256, 0, stream>>>(x, w_qkv, qkvp, 1024, 1536, 512, 2);
    reduce_k<2, false, false><<<1536, 256, 0, stream>>>(qkvp, nullptr, qkv, 1024 * 1536, 1536);
    rope_table_k<<<128, 256, 0, stream>>>(cost, sint);
    rope_apply_k<<<1024, 256, 0, stream>>>(qkv, cost, sint, rq, rk);
    tkv_k<<<2048, 256, 0, stream>>>(qkv, k_pos, v_pos, tk, tv);
    gemm_comp_k<<<dim3(4, 32, 8), 256, 0, stream>>>(tk, kc_w1, tv, vc_w1, compp, 256, 2048, 2048);
    reduce_k<4, true, true><<<512, 256, 0, stream>>>(compp, kc_b1, hk, 256 * 2048, 2048);
    reduce_k<4, true, true><<<512, 256, 0, stream>>>(compp + 4u * 256 * 2048, vc_b1, hv, 256 * 2048, 2048);
    gemm_skinny_z2_k<<<dim3(256, 1, 2), 256, 0, stream>>>(hk, kc_w2, kc_b2, ckc, hv, vc_w2, vc_b2, cvc, 2048);
    attn_fused_k<<<dim3(256, 8), 256, 0, stream>>>(qkv, rq, rk, ckc, cvc, mem_kv, strat, att);
    gemm_sk_k<<<dim3(16, 8, 4), 256, 0, stream>>>(att, out_w, outp, 1024, 512, 512, 4);
    reduce_k<4, false, false><<<512, 256, 0, stream>>>(outp, nullptr, out, 1024 * 512, 512);
}

// Round 8
// 385.983 us; speedup vs baseline: 1.0020x; 1.0020x over previous
//
#include <hip/hip_runtime.h>
#include <hip/hip_bf16.h>
#include <cfloat>
#include <math.h>

// Problem constants
#define S_LEN 1024
#define DIM 512
#define H_N 8
#define DH 64
#define CB 32
#define NB 32
#define NSEL 4
#define NMEM 4
#define WIN 64
#define SCALE 0.125f
#define EPS 1.1920929e-07f

// ---------------- ws layout (float offsets), total 9527296 f = 38.1 MB ----------------
// x dead after qkv GEMM -> rkT reuses it. qkvp dead after reduce_qkv -> compp/outp reuse.
#define OFF_X      0u          // 524288 (also rkT after transpose)
#define OFF_RKT    0u
#define OFF_QKV    524288u     // 1024*1536
#define OFF_RQ     2097152u    // 524288
#define OFF_RK     2621440u    // 524288 (dead after transpose)
#define OFF_VBUF   3145728u    // 524288  v as [h][s][64]
#define OFF_CKT    3670016u    // 8*2304 = 18432 (padded region 32768)
#define OFF_CVC    3702784u    // 16384
#define OFF_STRAT  3735552u    // 24576
#define OFF_ATT    3760128u    // 524288
#define OFF_HK     4284416u    // 2*524288 (hk then hv contiguous)
#define OFF_QKVP   5332992u    // 2*1572864 = 3145728
#define OFF_COMPP  5332992u    // 8*524288 = 4194304 (after qkvp dead)
#define OFF_OUTP   5332992u    // 4*524288 (after compp dead)

// ---------------- RMSNorm + strategy gates (fused) ----------------
__global__ void rmsnorm_strat_k(const float* __restrict__ inp, const float* __restrict__ g,
                                const float* __restrict__ sw, const float* __restrict__ sb,
                                float* __restrict__ x, float* __restrict__ strat) {
    int s = blockIdx.x;
    int t = threadIdx.x;
    __shared__ __align__(16) float xs[512];
    __shared__ float red[24][8];
    float v0 = inp[s * DIM + t];
    float v1 = inp[s * DIM + t + 256];
    float ss = v0 * v0 + v1 * v1;
    for (int o = 32; o > 0; o >>= 1) ss += __shfl_xor(ss, o);
    __shared__ float wsum[4];
    int wid = t >> 6, lane = t & 63;
    if (lane == 0) wsum[wid] = ss;
    __syncthreads();
    float tot = wsum[0] + wsum[1] + wsum[2] + wsum[3];
    float scale = 1.0f / sqrtf(tot / (float)DIM + EPS);
    float x0 = v0 * scale * g[t];
    float x1 = v1 * scale * g[t + 256];
    x[s * DIM + t]       = x0;
    x[s * DIM + t + 256] = x1;
    xs[t] = x0;
    xs[t + 256] = x1;
    __syncthreads();
    if (t < 192) {
        int o = t >> 3, p = t & 7;
        float acc = 0.0f;
        const float* xb = xs + p * 64;
        for (int k = 0; k < 64; ++k) acc += xb[k] * sw[(p * 64 + k) * 24 + o];
        red[o][p] = acc;
    }
    __syncthreads();
    if (t < 24) {
        float a = sb[t];
        for (int p = 0; p < 8; ++p) a += red[t][p];
        strat[s * 24 + t] = 1.0f / (1.0f + expf(-a));
    }
}

// ---------------- f32 GEMM 64x64 tile, split-K partial writer (generic) ----------------
__device__ __forceinline__ void gemm_sk_body(const float* __restrict__ A, const float* __restrict__ B,
                                             float* __restrict__ P, int M, int N, int K,
                                             int kstart, int Ks) {
    __shared__ __align__(16) float As[2][16][68];
    __shared__ __align__(16) float Bs[2][16][64];
    const int bm = blockIdx.x * 64, bn = blockIdx.y * 64;
    const int tid = threadIdx.x;
    const int tx = tid & 15, ty = tid >> 4;
    const int ar = tid >> 2;
    const int ac = (tid & 3) * 4;
    const int br = tid >> 4;
    const int bc = (tid & 15) * 4;
    const float* Aptr = A + (size_t)(bm + ar) * K + kstart + ac;
    const float* Bptr = B + (size_t)(kstart + br) * N + bn + bc;

    float4 a4 = *(const float4*)(Aptr);
    float4 b4 = *(const float4*)(Bptr);
    float acc[4][4] = {};
    int buf = 0;
    for (int k0 = 0; k0 < Ks; k0 += 16) {
        As[buf][ac + 0][ar] = a4.x;
        As[buf][ac + 1][ar] = a4.y;
        As[buf][ac + 2][ar] = a4.z;
        As[buf][ac + 3][ar] = a4.w;
        *(float4*)&Bs[buf][br][bc] = b4;
        __syncthreads();
        if (k0 + 16 < Ks) {
            a4 = *(const float4*)(Aptr + k0 + 16);
            b4 = *(const float4*)(Bptr + (size_t)(k0 + 16) * N);
        }
#pragma unroll
        for (int kk = 0; kk < 16; ++kk) {
            const float4 af = *(const float4*)&As[buf][kk][ty * 4];
            const float4 bf = *(const float4*)&Bs[buf][kk][tx * 4];
            acc[0][0] += af.x * bf.x; acc[0][1] += af.x * bf.y; acc[0][2] += af.x * bf.z; acc[0][3] += af.x * bf.w;
            acc[1][0] += af.y * bf.x; acc[1][1] += af.y * bf.y; acc[1][2] += af.y * bf.z; acc[1][3] += af.y * bf.w;
            acc[2][0] += af.z * bf.x; acc[2][1] += af.z * bf.y; acc[2][2] += af.z * bf.z; acc[2][3] += af.z * bf.w;
            acc[3][0] += af.w * bf.x; acc[3][1] += af.w * bf.y; acc[3][2] += af.w * bf.z; acc[3][3] += af.w * bf.w;
        }
        buf ^= 1;
    }
#pragma unroll
    for (int i = 0; i < 4; ++i) {
        int m = bm + ty * 4 + i;
        float4 v;
        v.x = acc[i][0]; v.y = acc[i][1]; v.z = acc[i][2]; v.w = acc[i][3];
        *(float4*)&P[(size_t)m * N + bn + tx * 4] = v;
    }
}

__global__ void gemm_sk_k(const float* __restrict__ A, const float* __restrict__ B,
                          float* __restrict__ P, int M, int N, int K, int nsplit) {
    int kz = blockIdx.z;
    int Ks = K / nsplit;
    gemm_sk_body(A, B, P + (size_t)kz * M * N, M, N, K, kz * Ks, Ks);
}

// ---------------- qkv split-K reduce + emit vbuf [h][s][64] ----------------
__global__ void reduce_qkv_k(const float* __restrict__ P, float* __restrict__ qkv,
                             float* __restrict__ vbuf) {
    int idx4 = blockIdx.x * 256 + threadIdx.x;   // 393216 float4s
    const int mn4 = 393216;
    float4 v = ((const float4*)P)[idx4];
    float4 w = ((const float4*)P)[idx4 + mn4];
    v.x += w.x; v.y += w.y; v.z += w.z; v.w += w.w;
    ((float4*)qkv)[idx4] = v;
    int c = (idx4 % 384) * 4;      // col in [0,1536)  (384 not pow2 -> must use %, not &)
    if (c >= 1024) {
        int s = idx4 / 384;
        int h = (c - 1024) >> 6, d = (c - 1024) & 63;
        *(float4*)(vbuf + (size_t)h * 65536 + s * 64 + d) = v;
    }
}

// ---------------- RoPE apply (inline double-precision trig) ----------------
__global__ void rope_apply_k(const float* __restrict__ qkv,
                             float* __restrict__ rq, float* __restrict__ rk) {
    int idx = blockIdx.x * 256 + threadIdx.x;   // 1024*8*32 pairs
    int s = idx >> 8;
    int rem = idx & 255;
    int h = rem >> 5, i = rem & 31;
    double inv = pow(10000.0, -(double)i / 32.0);
    double ang = (double)s * inv;
    float c = (float)cos(ang), sn = (float)sin(ang);
    int qb = s * 1536 + h * 64 + 2 * i;
    float q0 = qkv[qb], q1 = qkv[qb + 1];
    int ob = s * 512 + h * 64 + 2 * i;
    rq[ob]     = q0 * c - q1 * sn;
    rq[ob + 1] = q1 * c + q0 * sn;
    float k0 = qkv[qb + 512], k1 = qkv[qb + 513];
    rk[ob]     = k0 * c - k1 * sn;
    rk[ob + 1] = k1 * c + k0 * sn;
}

// ---------------- transpose rk -> rkT[h][d][s]; also fill ckT mem slots ----------------
__global__ void transpose_rk_k(const float* __restrict__ rk, float* __restrict__ rkT,
                               const float* __restrict__ mem_kv, float* __restrict__ ckT) {
    int h = blockIdx.x, st = blockIdx.y, t = threadIdx.x;
    __shared__ float tile[64][65];
    int s0 = st * 64;
    int r = t >> 2, c0 = (t & 3) * 16;
    const float* src = rk + (size_t)(s0 + r) * 512 + h * 64 + c0;
#pragma unroll
    for (int q = 0; q < 4; ++q) {
        float4 v = *(const float4*)(src + q * 4);
        tile[r][c0 + q * 4 + 0] = v.x;
        tile[r][c0 + q * 4 + 1] = v.y;
        tile[r][c0 + q * 4 + 2] = v.z;
        tile[r][c0 + q * 4 + 3] = v.w;
    }
    __syncthreads();
    int wv = t >> 6, ls = t & 63;
    float* dst = rkT + (size_t)h * 65536 + s0 + ls;
#pragma unroll
    for (int p = 0; p < 16; ++p) {
        int d = p * 4 + wv;
        dst[(size_t)d * 1024] = tile[ls][d];
    }
    if (st == 0) {   // ckT[h][d][j] j<4 from mem_kv[0]
        int d = t >> 2, j = t & 3;
        ckT[h * 2304 + d * 36 + j] = mem_kv[h * 256 + j * 64 + d];
    }
}

// ---------------- comp-MLP layer1 GEMM with fused input build ----------------
// z in [0,8): g = z>>2 (k vs v), kz = z&3 K-split. A built on the fly from qkv + pos.
__global__ void gemm_comp_k(const float* __restrict__ qkv, const float* __restrict__ k_pos,
                            const float* __restrict__ v_pos, const float* __restrict__ kw1,
                            const float* __restrict__ vw1, float* __restrict__ P) {
    int z = blockIdx.z, g = z >> 2, kz = z & 3;
    const float* B = g ? vw1 : kw1;
    const float* pos = g ? v_pos : k_pos;
    const int qoff = g ? 1024 : 512;
    const int kstart = kz * 512;
    __shared__ __align__(16) float As[2][16][68];
    __shared__ __align__(16) float Bs[2][16][64];
    const int bm = blockIdx.x * 64, bn = blockIdx.y * 64;
    const int tid = threadIdx.x;
    const int tx = tid & 15, ty = tid >> 4;
    const int ar = tid >> 2, ac = (tid & 3) * 4;
    const int br = tid >> 4, bc = (tid & 15) * 4;
    const int m = bm + ar;
    const int hh = m >> 5, nb = m & 31;
    const float* qb = qkv + (size_t)(nb * 32) * 1536 + qoff + hh * 64;
    const float* pb = pos + hh * 2048;
    const float* Bptr = B + (size_t)(kstart + br) * 2048 + bn + bc;

    auto loadA = [&](int kk) {
        int cb = kk >> 6, d = kk & 63;
        float4 a = *(const float4*)(qb + (size_t)cb * 1536 + d);
        float4 p = *(const float4*)(pb + cb * 64 + d);
        a.x += p.x; a.y += p.y; a.z += p.z; a.w += p.w;
        return a;
    };

    float4 a4 = loadA(kstart + ac);
    float4 b4 = *(const float4*)Bptr;
    float acc[4][4] = {};
    int buf = 0;
    for (int k0 = 0; k0 < 512; k0 += 16) {
        As[buf][ac + 0][ar] = a4.x;
        As[buf][ac + 1][ar] = a4.y;
        As[buf][ac + 2][ar] = a4.z;
        As[buf][ac + 3][ar] = a4.w;
        *(float4*)&Bs[buf][br][bc] = b4;
        __syncthreads();
        if (k0 + 16 < 512) {
            a4 = loadA(kstart + ac + k0 + 16);
            b4 = *(const float4*)(Bptr + (size_t)(k0 + 16) * 2048);
        }
#pragma unroll
        for (int kk = 0; kk < 16; ++kk) {
            const float4 af = *(const float4*)&As[buf][kk][ty * 4];
            const float4 bf = *(const float4*)&Bs[buf][kk][tx * 4];
            acc[0][0] += af.x * bf.x; acc[0][1] += af.x * bf.y; acc[0][2] += af.x * bf.z; acc[0][3] += af.x * bf.w;
            acc[1][0] += af.y * bf.x; acc[1][1] += af.y * bf.y; acc[1][2] += af.y * bf.z; acc[1][3] += af.y * bf.w;
            acc[2][0] += af.z * bf.x; acc[2][1] += af.z * bf.y; acc[2][2] += af.z * bf.z; acc[2][3] += af.z * bf.w;
            acc[3][0] += af.w * bf.x; acc[3][1] += af.w * bf.y; acc[3][2] += af.w * bf.z; acc[3][3] += af.w * bf.w;
        }
        buf ^= 1;
    }
    float* Pz = P + (size_t)z * 524288;
#pragma unroll
    for (int i = 0; i < 4; ++i) {
        int mm = bm + ty * 4 + i;
        float4 v;
        v.x = acc[i][0]; v.y = acc[i][1]; v.z = acc[i][2]; v.w = acc[i][3];
        *(float4*)&Pz[(size_t)mm * 2048 + bn + tx * 4] = v;
    }
}

// ---------------- combined comp reduce: hk and hv (+bias,+relu) ----------------
__global__ void reduce_comp_k(const float* __restrict__ P, const float* __restrict__ kb,
                              const float* __restrict__ vb, float* __restrict__ hkv) {
    int idx4 = blockIdx.x * 256 + threadIdx.x;   // 262144 float4s total
    const int half4 = 131072;                     // per matrix
    int which = idx4 >= half4 ? 1 : 0;
    int l4 = idx4 - which * half4;
    const float4* p4 = (const float4*)P + (size_t)which * 4 * half4 + l4;
    float4 v = p4[0];
    float4 w1 = p4[half4], w2 = p4[2 * half4], w3 = p4[3 * (size_t)half4];
    v.x += w1.x + w2.x + w3.x; v.y += w1.y + w2.y + w3.y;
    v.z += w1.z + w2.z + w3.z; v.w += w1.w + w2.w + w3.w;
    int col = (l4 * 4) & 2047;
    const float* bias = (which ? vb : kb) + col;
    v.x = fmaxf(v.x + bias[0], 0.f); v.y = fmaxf(v.y + bias[1], 0.f);
    v.z = fmaxf(v.z + bias[2], 0.f); v.w = fmaxf(v.w + bias[3], 0.f);
    *(float4*)(hkv + (size_t)which * 524288 + (size_t)l4 * 4) = v;
}

// ---------------- generic split-K reduce (out proj) ----------------
template <int NS>
__global__ void reduce_k(const float* __restrict__ P, float* __restrict__ Y, int MN) {
    int idx4 = blockIdx.x * 256 + threadIdx.x;
    if (idx4 * 4 >= MN) return;
    const float4* p4 = (const float4*)P;
    int mn4 = MN >> 2;
    float4 v = p4[idx4];
#pragma unroll
    for (int j = 1; j < NS; ++j) {
        float4 w = p4[idx4 + (size_t)j * mn4];
        v.x += w.x; v.y += w.y; v.z += w.z; v.w += w.w;
    }
    ((float4*)Y)[idx4] = v;
}

// ---------------- skinny GEMM: layer2; z=0 -> ckT (transposed), z=1 -> cvc ----------------
__global__ void gemm_skinny_z2_k(const float* __restrict__ hkv, const float* __restrict__ kw2,
                                 const float* __restrict__ kb2, const float* __restrict__ vw2,
                                 const float* __restrict__ vb2, float* __restrict__ ckT,
                                 float* __restrict__ cvc) {
    int z = blockIdx.z;
    const float* A = hkv + (size_t)z * 524288;
    const float* B = z ? vw2 : kw2;
    const float* bias = z ? vb2 : kb2;
    int row = blockIdx.x;
    int col = threadIdx.x & 63;
    int chunk = threadIdx.x >> 6;
    const float* a = A + (size_t)row * 2048 + chunk * 512;
    const float* b = B + (size_t)chunk * 512 * 64;
    float acc = 0.0f;
    for (int k = 0; k < 512; k += 4) {
        float4 av = *(const float4*)(a + k);
        acc += av.x * b[(k + 0) * 64 + col];
        acc += av.y * b[(k + 1) * 64 + col];
        acc += av.z * b[(k + 2) * 64 + col];
        acc += av.w * b[(k + 3) * 64 + col];
    }
    __shared__ float red[4][64];
    red[chunk][col] = acc;
    __syncthreads();
    if (chunk == 0) {
        float v = red[0][col] + red[1][col] + red[2][col] + red[3][col] + bias[col];
        int hh = row >> 5, j = row & 31;
        if (z == 0) ckT[hh * 2304 + col * 36 + 4 + j] = v;
        else        cvc[(size_t)row * 64 + col] = v;
    }
}

// ---------------- helpers ----------------
__device__ __forceinline__ float redmax64(float v) {
    for (int o = 32; o > 0; o >>= 1) v = fmaxf(v, __shfl_xor(v, o));
    return v;
}
__device__ __forceinline__ float redsum64(float v) {
    for (int o = 32; o > 0; o >>= 1) v += __shfl_xor(v, o);
    return v;
}

// ---------------- fused attention: comp + topk + fine + slide + gates ----------------
// one 64-thread wave per (s, h); QK via transposed K (coalesced); PV via vbuf [h][s][64]
__global__ __launch_bounds__(64) void attn_fused_k(
    const float* __restrict__ qkv, const float* __restrict__ rq,
    const float* __restrict__ rkT, const float* __restrict__ ckT,
    const float* __restrict__ cvc, const float* __restrict__ mem_kv,
    const float* __restrict__ vbuf, const float* __restrict__ strat,
    float* __restrict__ att) {
    int s = blockIdx.x, h = blockIdx.y, lane = threadIdx.x;
    __shared__ __align__(16) float qs[64];
    __shared__ __align__(16) float rqs[64];
    __shared__ float paw[192];
    __shared__ int rww[192];
    qs[lane]  = qkv[s * 1536 + h * 64 + lane];
    rqs[lane] = rq[s * 512 + h * 64 + lane];
    __syncthreads();

    int own = s >> 5, p = s & 31, t31 = lane & 31;
    bool hiw = lane >= 32;
    int lo = (s > WIN) ? s - WIN : 0;
    int cnt = s - lo + 1;
    bool cvalid = (lane < NMEM) || (lane < 36 && (lane - NMEM + 1) * CB - 1 < s);
    int jc = (lane < 36) ? lane : 35;
    int rowC = own * 32 + t31;
    int rowSA = lo + lane;      if (rowSA > 1023) rowSA = 1023;
    int rowSB = lo + 64 + lane; if (rowSB > 1023) rowSB = 1023;
    const float* rkTh = rkT + (size_t)h * 65536;
    const float* ckTh = ckT + h * 2304;

    // ---- loop1: comp QK + own-block fine QK + slide QK (all coalesced over lanes) ----
    float c0 = 0, c1 = 0, f0 = 0, f1 = 0, a0 = 0, a1 = 0, b0 = 0, b1 = 0;
#pragma unroll 4
    for (int d = 0; d < 64; d += 2) {
        float qd0 = qs[d], qd1 = qs[d + 1];
        float rd0 = rqs[d], rd1 = rqs[d + 1];
        const float* r0 = rkTh + (size_t)d * 1024;
        const float* r1 = r0 + 1024;
        c0 += qd0 * ckTh[d * 36 + jc];
        c1 += qd1 * ckTh[(d + 1) * 36 + jc];
        f0 += rd0 * r0[rowC];  f1 += rd1 * r1[rowC];
        a0 += rd0 * r0[rowSA]; a1 += rd1 * r1[rowSA];
        b0 += rd0 * r0[rowSB]; b1 += rd1 * r1[rowSB];
    }

    // ---- comp softmax ----
    float simc = cvalid ? (c0 + c1) * SCALE : -FLT_MAX;
    float mx = redmax64(simc);
    float e = (simc == -FLT_MAX) ? 0.0f : expf(simc - mx);
    float tot = redsum64(e);
    float a = e / tot;
    paw[lane] = (lane < 36) ? a : 0.0f;
    __syncthreads();
    // comp PV (coalesced rows)
    float cacc;
    {
        const float* mv = mem_kv + 2048 + h * 256 + lane;
        cacc = paw[0] * mv[0] + paw[1] * mv[64] + paw[2] * mv[128] + paw[3] * mv[192];
        const float* cvb = cvc + h * 2048 + lane;
        for (int j = 0; j < 32; ++j) cacc += paw[4 + j] * cvb[j * 64];
    }

    // ---- top-4 (wave-parallel, lowest-index tie-break) ----
    float tval = (lane >= NMEM && lane < 36) ? a : -1.0f;
    int tidx = lane - NMEM;
    int sel0, sel1, sel2, sel3, msk = 0;
#pragma unroll
    for (int t = 0; t < NSEL; ++t) {
        float bv = tval; int bi = tidx;
        for (int o = 32; o > 0; o >>= 1) {
            float ov = __shfl_xor(bv, o);
            int oi = __shfl_xor(bi, o);
            if (ov > bv || (ov == bv && oi < bi)) { bv = ov; bi = oi; }
        }
        if (t == 0) sel0 = bi; else if (t == 1) sel1 = bi;
        else if (t == 2) sel2 = bi; else sel3 = bi;
        if (bv > 1e-10f) msk |= 1 << t;
        if (tidx == bi && lane >= NMEM && lane < 36) tval = -1.0f;
    }

    // ---- loop2: fine QK for selected blocks (coalesced) ----
    int rowA = (hiw ? sel1 : sel0) * 32 + t31;
    int rowB = (hiw ? sel3 : sel2) * 32 + t31;
    float A0 = 0, A1 = 0, B0 = 0, B1 = 0;
#pragma unroll 4
    for (int d = 0; d < 64; d += 2) {
        float rd0 = rqs[d], rd1 = rqs[d + 1];
        const float* r0 = rkTh + (size_t)d * 1024;
        const float* r1 = r0 + 1024;
        A0 += rd0 * r0[rowA]; A1 += rd1 * r1[rowA];
        B0 += rd0 * r0[rowB]; B1 += rd1 * r1[rowB];
    }
    bool valA = hiw ? ((msk >> 1) & 1) : (msk & 1);
    bool valB = hiw ? ((msk >> 3) & 1) : ((msk >> 2) & 1);
    bool valC = (!hiw) && (t31 <= p);
    float simA = valA ? (A0 + A1) * SCALE : -FLT_MAX;
    float simB = valB ? (B0 + B1) * SCALE : -FLT_MAX;
    float simC = valC ? (f0 + f1) * SCALE : -FLT_MAX;

    // ---- fine softmax + PV ----
    float fmx = redmax64(fmaxf(fmaxf(simA, simB), simC));
    float eA = (simA == -FLT_MAX) ? 0.0f : expf(simA - fmx);
    float eB = (simB == -FLT_MAX) ? 0.0f : expf(simB - fmx);
    float eC = (simC == -FLT_MAX) ? 0.0f : expf(simC - fmx);
    float fsum = redsum64(eA + eB + eC);
    float finv = 1.0f / fsum;
    __syncthreads();
    paw[lane] = eA * finv;        rww[lane] = rowA;
    paw[64 + lane] = eB * finv;   rww[64 + lane] = rowB;
    paw[128 + lane] = eC * finv;  rww[128 + lane] = rowC;
    __syncthreads();
    const float* vh = vbuf + (size_t)h * 65536 + lane;
    float facc = 0.0f;
    for (int kk = 0; kk < 160; ++kk) {
        float w = paw[kk];
        if (w != 0.0f) facc += w * vh[(size_t)rww[kk] * 64];
    }
    __syncthreads();

    // ---- sliding-window softmax + PV (sims from loop1) ----
    float sA = (lane < cnt) ? (a0 + a1) * SCALE : -FLT_MAX;
    float sB = (64 + lane < cnt) ? (b0 + b1) * SCALE : -FLT_MAX;
    float smx = redmax64(fmaxf(sA, sB));
    float esA = (sA == -FLT_MAX) ? 0.0f : expf(sA - smx);
    float esB = (sB == -FLT_MAX) ? 0.0f : expf(sB - smx);
    float ssum = redsum64(esA + esB);
    float sinv = 1.0f / ssum;
    paw[lane] = esA * sinv;
    if (64 + lane < cnt) paw[64 + lane] = esB * sinv;
    __syncthreads();
    float sacc = 0.0f;
    const float* vlo = vh + (size_t)lo * 64;
    for (int kk = 0; kk < cnt; ++kk)
        sacc += paw[kk] * vlo[(size_t)kk * 64];

    // ---- gated combine ----
    const float* st = strat + s * 24 + h * 3;
    att[s * 512 + h * 64 + lane] = st[0] * cacc + st[1] * facc + st[2] * sacc;
}

extern "C" void kernel_launch(void* const* d_in, const int* in_sizes, int n_in,
                              void* d_out, int out_size, void* d_ws, size_t ws_size,
                              hipStream_t stream) {
    const float* inp     = (const float*)d_in[0];
    const float* norm_g  = (const float*)d_in[1];
    const float* w_qkv   = (const float*)d_in[2];
    const float* k_pos   = (const float*)d_in[3];
    const float* v_pos   = (const float*)d_in[4];
    const float* kc_w1   = (const float*)d_in[5];
    const float* kc_b1   = (const float*)d_in[6];
    const float* kc_w2   = (const float*)d_in[7];
    const float* kc_b2   = (const float*)d_in[8];
    const float* vc_w1   = (const float*)d_in[9];
    const float* vc_b1   = (const float*)d_in[10];
    const float* vc_w2   = (const float*)d_in[11];
    const float* vc_b2   = (const float*)d_in[12];
    const float* mem_kv  = (const float*)d_in[13];
    const float* strat_w = (const float*)d_in[14];
    const float* strat_b = (const float*)d_in[15];
    const float* out_w   = (const float*)d_in[16];
    float* out = (float*)d_out;

    float* ws = (float*)d_ws;
    float* x     = ws + OFF_X;
    float* rkT   = ws + OFF_RKT;
    float* qkv   = ws + OFF_QKV;
    float* rq    = ws + OFF_RQ;
    float* rk    = ws + OFF_RK;
    float* vbuf  = ws + OFF_VBUF;
    float* ckT   = ws + OFF_CKT;
    float* cvc   = ws + OFF_CVC;
    float* strat = ws + OFF_STRAT;
    float* att   = ws + OFF_ATT;
    float* hkv   = ws + OFF_HK;
    float* qkvp  = ws + OFF_QKVP;
    float* compp = ws + OFF_COMPP;
    float* outp  = ws + OFF_OUTP;

    rmsnorm_strat_k<<<1024, 256, 0, stream>>>(inp, norm_g, strat_w, strat_b, x, strat);
    gemm_sk_k<<<dim3(16, 24, 2), 256, 0, stream>>>(x, w_qkv, qkvp, 1024, 1536, 512, 2);
    reduce_qkv_k<<<1536, 256, 0, stream>>>(qkvp, qkv, vbuf);
    rope_apply_k<<<1024, 256, 0, stream>>>(qkv, rq, rk);
    transpose_rk_k<<<dim3(8, 16), 256, 0, stream>>>(rk, rkT, mem_kv, ckT);
    gemm_comp_k<<<dim3(4, 32, 8), 256, 0, stream>>>(qkv, k_pos, v_pos, kc_w1, vc_w1, compp);
    reduce_comp_k<<<1024, 256, 0, stream>>>(compp, kc_b1, vc_b1, hkv);
    gemm_skinny_z2_k<<<dim3(256, 1, 2), 256, 0, stream>>>(hkv, kc_w2, kc_b2, vc_w2, vc_b2, ckT, cvc);
    attn_fused_k<<<dim3(1024, 8), 64, 0, stream>>>(qkv, rq, rkT, ckT, cvc, mem_kv, vbuf, strat, att);
    gemm_sk_k<<<dim3(16, 8, 4), 256, 0, stream>>>(att, out_w, outp, 1024, 512, 512, 4);
    reduce_k<4><<<512, 256, 0, stream>>>(outp, out, 1024 * 512);
}

// Round 10
// 362.836 us; speedup vs baseline: 1.0659x; 1.0638x over previous
//
#include <hip/hip_runtime.h>
#include <hip/hip_bf16.h>
#include <cfloat>
#include <math.h>

// Problem constants
#define S_LEN 1024
#define DIM 512
#define H_N 8
#define DH 64
#define CB 32
#define NB 32
#define NSEL 4
#define NMEM 4
#define WIN 64
#define SCALE 0.125f
#define EPS 1.1920929e-07f

// ---------------- ws layout (float offsets) ----------------
#define OFF_X      0u          // 524288 (dead after qkv GEMM)
#define OFF_QKV    524288u     // 1024*1536
#define OFF_RQ     2097152u    // 524288
#define OFF_RK     2621440u    // 524288 (live through attn)
#define OFF_VBUF   3145728u    // 524288  v as [h][s][64]
#define OFF_CKC    3670016u    // 16384 (8*32*64)
#define OFF_CVC    3702784u    // 16384
#define OFF_STRAT  3735552u    // 24576
#define OFF_ATT    3760128u    // 524288
#define OFF_HK     4284416u    // 2*524288 (hk then hv contiguous)
#define OFF_QKVP   5332992u    // 2*1572864
#define OFF_COMPP  5332992u    // 8*524288 (after qkvp dead)
#define OFF_OUTP   5332992u    // 4*524288 (after compp dead)

// ---------------- RMSNorm + strategy gates (fused) ----------------
__global__ void rmsnorm_strat_k(const float* __restrict__ inp, const float* __restrict__ g,
                                const float* __restrict__ sw, const float* __restrict__ sb,
                                float* __restrict__ x, float* __restrict__ strat) {
    int s = blockIdx.x;
    int t = threadIdx.x;
    __shared__ __align__(16) float xs[512];
    __shared__ float red[24][8];
    float v0 = inp[s * DIM + t];
    float v1 = inp[s * DIM + t + 256];
    float ss = v0 * v0 + v1 * v1;
    for (int o = 32; o > 0; o >>= 1) ss += __shfl_xor(ss, o);
    __shared__ float wsum[4];
    int wid = t >> 6, lane = t & 63;
    if (lane == 0) wsum[wid] = ss;
    __syncthreads();
    float tot = wsum[0] + wsum[1] + wsum[2] + wsum[3];
    float scale = 1.0f / sqrtf(tot / (float)DIM + EPS);
    float x0 = v0 * scale * g[t];
    float x1 = v1 * scale * g[t + 256];
    x[s * DIM + t]       = x0;
    x[s * DIM + t + 256] = x1;
    xs[t] = x0;
    xs[t + 256] = x1;
    __syncthreads();
    if (t < 192) {
        int o = t >> 3, p = t & 7;
        float acc = 0.0f;
        const float* xb = xs + p * 64;
        for (int k = 0; k < 64; ++k) acc += xb[k] * sw[(p * 64 + k) * 24 + o];
        red[o][p] = acc;
    }
    __syncthreads();
    if (t < 24) {
        float a = sb[t];
        for (int p = 0; p < 8; ++p) a += red[t][p];
        strat[s * 24 + t] = 1.0f / (1.0f + expf(-a));
    }
}

// ---------------- f32 GEMM 64x64 tile, split-K partial writer (generic) ----------------
__device__ __forceinline__ void gemm_sk_body(const float* __restrict__ A, const float* __restrict__ B,
                                             float* __restrict__ P, int M, int N, int K,
                                             int kstart, int Ks) {
    __shared__ __align__(16) float As[2][16][68];
    __shared__ __align__(16) float Bs[2][16][64];
    const int bm = blockIdx.x * 64, bn = blockIdx.y * 64;
    const int tid = threadIdx.x;
    const int tx = tid & 15, ty = tid >> 4;
    const int ar = tid >> 2;
    const int ac = (tid & 3) * 4;
    const int br = tid >> 4;
    const int bc = (tid & 15) * 4;
    const float* Aptr = A + (size_t)(bm + ar) * K + kstart + ac;
    const float* Bptr = B + (size_t)(kstart + br) * N + bn + bc;

    float4 a4 = *(const float4*)(Aptr);
    float4 b4 = *(const float4*)(Bptr);
    float acc[4][4] = {};
    int buf = 0;
    for (int k0 = 0; k0 < Ks; k0 += 16) {
        As[buf][ac + 0][ar] = a4.x;
        As[buf][ac + 1][ar] = a4.y;
        As[buf][ac + 2][ar] = a4.z;
        As[buf][ac + 3][ar] = a4.w;
        *(float4*)&Bs[buf][br][bc] = b4;
        __syncthreads();
        if (k0 + 16 < Ks) {
            a4 = *(const float4*)(Aptr + k0 + 16);
            b4 = *(const float4*)(Bptr + (size_t)(k0 + 16) * N);
        }
#pragma unroll
        for (int kk = 0; kk < 16; ++kk) {
            const float4 af = *(const float4*)&As[buf][kk][ty * 4];
            const float4 bf = *(const float4*)&Bs[buf][kk][tx * 4];
            acc[0][0] += af.x * bf.x; acc[0][1] += af.x * bf.y; acc[0][2] += af.x * bf.z; acc[0][3] += af.x * bf.w;
            acc[1][0] += af.y * bf.x; acc[1][1] += af.y * bf.y; acc[1][2] += af.y * bf.z; acc[1][3] += af.y * bf.w;
            acc[2][0] += af.z * bf.x; acc[2][1] += af.z * bf.y; acc[2][2] += af.z * bf.z; acc[2][3] += af.z * bf.w;
            acc[3][0] += af.w * bf.x; acc[3][1] += af.w * bf.y; acc[3][2] += af.w * bf.z; acc[3][3] += af.w * bf.w;
        }
        buf ^= 1;
    }
#pragma unroll
    for (int i = 0; i < 4; ++i) {
        int m = bm + ty * 4 + i;
        float4 v;
        v.x = acc[i][0]; v.y = acc[i][1]; v.z = acc[i][2]; v.w = acc[i][3];
        *(float4*)&P[(size_t)m * N + bn + tx * 4] = v;
    }
}

__global__ void gemm_sk_k(const float* __restrict__ A, const float* __restrict__ B,
                          float* __restrict__ P, int M, int N, int K, int nsplit) {
    int kz = blockIdx.z;
    int Ks = K / nsplit;
    gemm_sk_body(A, B, P + (size_t)kz * M * N, M, N, K, kz * Ks, Ks);
}

// ---------------- qkv split-K reduce + emit vbuf [h][s][64] ----------------
__global__ void reduce_qkv_k(const float* __restrict__ P, float* __restrict__ qkv,
                             float* __restrict__ vbuf) {
    int idx4 = blockIdx.x * 256 + threadIdx.x;   // 393216 float4s
    const int mn4 = 393216;
    float4 v = ((const float4*)P)[idx4];
    float4 w = ((const float4*)P)[idx4 + mn4];
    v.x += w.x; v.y += w.y; v.z += w.z; v.w += w.w;
    ((float4*)qkv)[idx4] = v;
    int c = (idx4 % 384) * 4;      // col in [0,1536)  (384 not pow2 -> must use %, not &)
    if (c >= 1024) {
        int s = idx4 / 384;
        int h = (c - 1024) >> 6, d = (c - 1024) & 63;
        *(float4*)(vbuf + (size_t)h * 65536 + s * 64 + d) = v;
    }
}

// ---------------- RoPE apply (inline double-precision trig) ----------------
__global__ void rope_apply_k(const float* __restrict__ qkv,
                             float* __restrict__ rq, float* __restrict__ rk) {
    int idx = blockIdx.x * 256 + threadIdx.x;   // 1024*8*32 pairs
    int s = idx >> 8;
    int rem = idx & 255;
    int h = rem >> 5, i = rem & 31;
    double inv = pow(10000.0, -(double)i / 32.0);
    double ang = (double)s * inv;
    float c = (float)cos(ang), sn = (float)sin(ang);
    int qb = s * 1536 + h * 64 + 2 * i;
    float q0 = qkv[qb], q1 = qkv[qb + 1];
    int ob = s * 512 + h * 64 + 2 * i;
    rq[ob]     = q0 * c - q1 * sn;
    rq[ob + 1] = q1 * c + q0 * sn;
    float k0 = qkv[qb + 512], k1 = qkv[qb + 513];
    rk[ob]     = k0 * c - k1 * sn;
    rk[ob + 1] = k1 * c + k0 * sn;
}

// ---------------- comp-MLP layer1 GEMM with fused input build ----------------
__global__ void gemm_comp_k(const float* __restrict__ qkv, const float* __restrict__ k_pos,
                            const float* __restrict__ v_pos, const float* __restrict__ kw1,
                            const float* __restrict__ vw1, float* __restrict__ P) {
    int z = blockIdx.z, g = z >> 2, kz = z & 3;
    const float* B = g ? vw1 : kw1;
    const float* pos = g ? v_pos : k_pos;
    const int qoff = g ? 1024 : 512;
    const int kstart = kz * 512;
    __shared__ __align__(16) float As[2][16][68];
    __shared__ __align__(16) float Bs[2][16][64];
    const int bm = blockIdx.x * 64, bn = blockIdx.y * 64;
    const int tid = threadIdx.x;
    const int tx = tid & 15, ty = tid >> 4;
    const int ar = tid >> 2, ac = (tid & 3) * 4;
    const int br = tid >> 4, bc = (tid & 15) * 4;
    const int m = bm + ar;
    const int hh = m >> 5, nb = m & 31;
    const float* qb = qkv + (size_t)(nb * 32) * 1536 + qoff + hh * 64;
    const float* pb = pos + hh * 2048;
    const float* Bptr = B + (size_t)(kstart + br) * 2048 + bn + bc;

    auto loadA = [&](int kk) {
        int cb = kk >> 6, d = kk & 63;
        float4 a = *(const float4*)(qb + (size_t)cb * 1536 + d);
        float4 p = *(const float4*)(pb + cb * 64 + d);
        a.x += p.x; a.y += p.y; a.z += p.z; a.w += p.w;
        return a;
    };

    float4 a4 = loadA(kstart + ac);
    float4 b4 = *(const float4*)Bptr;
    float acc[4][4] = {};
    int buf = 0;
    for (int k0 = 0; k0 < 512; k0 += 16) {
        As[buf][ac + 0][ar] = a4.x;
        As[buf][ac + 1][ar] = a4.y;
        As[buf][ac + 2][ar] = a4.z;
        As[buf][ac + 3][ar] = a4.w;
        *(float4*)&Bs[buf][br][bc] = b4;
        __syncthreads();
        if (k0 + 16 < 512) {
            a4 = loadA(kstart + ac + k0 + 16);
            b4 = *(const float4*)(Bptr + (size_t)(k0 + 16) * 2048);
        }
#pragma unroll
        for (int kk = 0; kk < 16; ++kk) {
            const float4 af = *(const float4*)&As[buf][kk][ty * 4];
            const float4 bf = *(const float4*)&Bs[buf][kk][tx * 4];
            acc[0][0] += af.x * bf.x; acc[0][1] += af.x * bf.y; acc[0][2] += af.x * bf.z; acc[0][3] += af.x * bf.w;
            acc[1][0] += af.y * bf.x; acc[1][1] += af.y * bf.y; acc[1][2] += af.y * bf.z; acc[1][3] += af.y * bf.w;
            acc[2][0] += af.z * bf.x; acc[2][1] += af.z * bf.y; acc[2][2] += af.z * bf.z; acc[2][3] += af.z * bf.w;
            acc[3][0] += af.w * bf.x; acc[3][1] += af.w * bf.y; acc[3][2] += af.w * bf.z; acc[3][3] += af.w * bf.w;
        }
        buf ^= 1;
    }
    float* Pz = P + (size_t)z * 524288;
#pragma unroll
    for (int i = 0; i < 4; ++i) {
        int mm = bm + ty * 4 + i;
        float4 v;
        v.x = acc[i][0]; v.y = acc[i][1]; v.z = acc[i][2]; v.w = acc[i][3];
        *(float4*)&Pz[(size_t)mm * 2048 + bn + tx * 4] = v;
    }
}

// ---------------- combined comp reduce: hk and hv (+bias,+relu) ----------------
__global__ void reduce_comp_k(const float* __restrict__ P, const float* __restrict__ kb,
                              const float* __restrict__ vb, float* __restrict__ hkv) {
    int idx4 = blockIdx.x * 256 + threadIdx.x;   // 262144 float4s total
    const int half4 = 131072;                     // per matrix
    int which = idx4 >= half4 ? 1 : 0;
    int l4 = idx4 - which * half4;
    const float4* p4 = (const float4*)P + (size_t)which * 4 * half4 + l4;
    float4 v = p4[0];
    float4 w1 = p4[half4], w2 = p4[2 * half4], w3 = p4[3 * (size_t)half4];
    v.x += w1.x + w2.x + w3.x; v.y += w1.y + w2.y + w3.y;
    v.z += w1.z + w2.z + w3.z; v.w += w1.w + w2.w + w3.w;
    int col = (l4 * 4) & 2047;
    const float* bias = (which ? vb : kb) + col;
    v.x = fmaxf(v.x + bias[0], 0.f); v.y = fmaxf(v.y + bias[1], 0.f);
    v.z = fmaxf(v.z + bias[2], 0.f); v.w = fmaxf(v.w + bias[3], 0.f);
    *(float4*)(hkv + (size_t)which * 524288 + (size_t)l4 * 4) = v;
}

// ---------------- generic split-K reduce (out proj) ----------------
template <int NS>
__global__ void reduce_k(const float* __restrict__ P, float* __restrict__ Y, int MN) {
    int idx4 = blockIdx.x * 256 + threadIdx.x;
    if (idx4 * 4 >= MN) return;
    const float4* p4 = (const float4*)P;
    int mn4 = MN >> 2;
    float4 v = p4[idx4];
#pragma unroll
    for (int j = 1; j < NS; ++j) {
        float4 w = p4[idx4 + (size_t)j * mn4];
        v.x += w.x; v.y += w.y; v.z += w.z; v.w += w.w;
    }
    ((float4*)Y)[idx4] = v;
}

// ---------------- skinny GEMM: layer2 -> ckc / cvc (both row-major) ----------------
__global__ void gemm_skinny_z2_k(const float* __restrict__ hkv, const float* __restrict__ kw2,
                                 const float* __restrict__ kb2, const float* __restrict__ vw2,
                                 const float* __restrict__ vb2, float* __restrict__ ckc,
                                 float* __restrict__ cvc) {
    int z = blockIdx.z;
    const float* A = hkv + (size_t)z * 524288;
    const float* B = z ? vw2 : kw2;
    const float* bias = z ? vb2 : kb2;
    int row = blockIdx.x;
    int col = threadIdx.x & 63;
    int chunk = threadIdx.x >> 6;
    const float* a = A + (size_t)row * 2048 + chunk * 512;
    const float* b = B + (size_t)chunk * 512 * 64;
    float acc = 0.0f;
    for (int k = 0; k < 512; k += 4) {
        float4 av = *(const float4*)(a + k);
        acc += av.x * b[(k + 0) * 64 + col];
        acc += av.y * b[(k + 1) * 64 + col];
        acc += av.z * b[(k + 2) * 64 + col];
        acc += av.w * b[(k + 3) * 64 + col];
    }
    __shared__ float red[4][64];
    red[chunk][col] = acc;
    __syncthreads();
    if (chunk == 0) {
        float v = red[0][col] + red[1][col] + red[2][col] + red[3][col] + bias[col];
        if (z == 0) ckc[(size_t)row * 64 + col] = v;
        else        cvc[(size_t)row * 64 + col] = v;
    }
}

// ---------------- helpers ----------------
__device__ __forceinline__ float redmax64(float v) {
    for (int o = 32; o > 0; o >>= 1) v = fmaxf(v, __shfl_xor(v, o));
    return v;
}
__device__ __forceinline__ float redsum64(float v) {
    for (int o = 32; o > 0; o >>= 1) v += __shfl_xor(v, o);
    return v;
}
// broadcast-dot: q distributed over lanes (q[lane]=qv), each lane has its own k row.
// __shfl with constant index -> v_readlane (SGPR broadcast), 4 independent chains.
__device__ __forceinline__ float bdot(float qv, const float* __restrict__ krow) {
    const float4* k4 = (const float4*)krow;
    float a0 = 0, a1 = 0, a2 = 0, a3 = 0;
#pragma unroll
    for (int i = 0; i < 4; ++i) {
        float4 ka = k4[4 * i], kb = k4[4 * i + 1], kc = k4[4 * i + 2], kd = k4[4 * i + 3];
        int b = 16 * i;
        a0 += __shfl(qv, b + 0) * ka.x + __shfl(qv, b + 1) * ka.y + __shfl(qv, b + 2) * ka.z + __shfl(qv, b + 3) * ka.w;
        a1 += __shfl(qv, b + 4) * kb.x + __shfl(qv, b + 5) * kb.y + __shfl(qv, b + 6) * kb.z + __shfl(qv, b + 7) * kb.w;
        a2 += __shfl(qv, b + 8) * kc.x + __shfl(qv, b + 9) * kc.y + __shfl(qv, b + 10) * kc.z + __shfl(qv, b + 11) * kc.w;
        a3 += __shfl(qv, b + 12) * kd.x + __shfl(qv, b + 13) * kd.y + __shfl(qv, b + 14) * kd.z + __shfl(qv, b + 15) * kd.w;
    }
    return (a0 + a1) + (a2 + a3);
}

// ---------------- fused attention: zero LDS, zero barriers ----------------
// 256-thread blocks = 4 fully independent waves; wave w -> s = blockIdx.x*4+w, h = blockIdx.y
__global__ __launch_bounds__(256) void attn_fused_k(
    const float* __restrict__ qkv, const float* __restrict__ rq,
    const float* __restrict__ rk, const float* __restrict__ ckc,
    const float* __restrict__ cvc, const float* __restrict__ mem_kv,
    const float* __restrict__ vbuf, const float* __restrict__ strat,
    float* __restrict__ att) {
    const int lane = threadIdx.x & 63;
    const int s = blockIdx.x * 4 + (threadIdx.x >> 6);
    const int h = blockIdx.y;

    const float qv  = qkv[s * 1536 + h * 64 + lane];
    const float rqv = rq[s * 512 + h * 64 + lane];

    // ---- compressed attention QK (key = lane, 36 keys) ----
    bool cvalid = (lane < NMEM) || (lane < 36 && (lane - NMEM + 1) * CB - 1 < s);
    int jcl = (lane < 36 && lane >= NMEM) ? lane - NMEM : 0;
    const float* ckrow = (lane < NMEM) ? (mem_kv + (h * 4 + lane) * 64)
                                       : (ckc + (size_t)(h * 32 + jcl) * 64);
    float simc = bdot(qv, ckrow) * SCALE;
    simc = cvalid ? simc : -FLT_MAX;
    float mx = redmax64(simc);
    float e = (simc == -FLT_MAX) ? 0.0f : expf(simc - mx);
    float tot = redsum64(e);
    float ca = e / tot;           // comp weight for key=lane (lane<36)

    // ---- comp PV (rows uniform; lane = d) ----
    float cacc;
    {
        const float* mv = mem_kv + 2048 + h * 256 + lane;
        float c0 = __shfl(ca, 0) * mv[0];
        float c1 = __shfl(ca, 1) * mv[64];
        float c2 = __shfl(ca, 2) * mv[128];
        float c3 = __shfl(ca, 3) * mv[192];
        const float* cvb = cvc + h * 2048 + lane;
#pragma unroll
        for (int j = 0; j < 32; j += 4) {
            c0 += __shfl(ca, 4 + j) * cvb[(j + 0) * 64];
            c1 += __shfl(ca, 5 + j) * cvb[(j + 1) * 64];
            c2 += __shfl(ca, 6 + j) * cvb[(j + 2) * 64];
            c3 += __shfl(ca, 7 + j) * cvb[(j + 3) * 64];
        }
        cacc = (c0 + c1) + (c2 + c3);
    }

    // ---- top-4 (wave-parallel, lowest-index tie-break) ----
    float tval = (lane >= NMEM && lane < 36) ? ca : -1.0f;
    int tidx = lane - NMEM;
    int sel0, sel1, sel2, sel3, msk = 0;
#pragma unroll
    for (int t = 0; t < NSEL; ++t) {
        float bv = tval; int bi = tidx;
        for (int o = 32; o > 0; o >>= 1) {
            float ov = __shfl_xor(bv, o);
            int oi = __shfl_xor(bi, o);
            if (ov > bv || (ov == bv && oi < bi)) { bv = ov; bi = oi; }
        }
        if (t == 0) sel0 = bi; else if (t == 1) sel1 = bi;
        else if (t == 2) sel2 = bi; else sel3 = bi;
        if (bv > 1e-10f) msk |= 1 << t;
        if (tidx == bi && lane >= NMEM && lane < 36) tval = -1.0f;
    }

    // ---- fine QK (per-lane rows, row-major rk) ----
    const int t31 = lane & 31;
    const bool hiw = lane >= 32;
    const int own = s >> 5, p = s & 31;
    const float* rkh = rk + h * 64;
    int rowA = (hiw ? sel1 : sel0) * 32 + t31;
    int rowB = (hiw ? sel3 : sel2) * 32 + t31;
    int rowC = own * 32 + t31;
    float simA = bdot(rqv, rkh + (size_t)rowA * 512) * SCALE;
    float simB = bdot(rqv, rkh + (size_t)rowB * 512) * SCALE;
    float simC = bdot(rqv, rkh + (size_t)rowC * 512) * SCALE;
    bool valA = hiw ? ((msk >> 1) & 1) : (msk & 1);
    bool valB = hiw ? ((msk >> 3) & 1) : ((msk >> 2) & 1);
    bool valC = (!hiw) && (t31 <= p);
    simA = valA ? simA : -FLT_MAX;
    simB = valB ? simB : -FLT_MAX;
    simC = valC ? simC : -FLT_MAX;

    float fmx = redmax64(fmaxf(fmaxf(simA, simB), simC));
    float eA = (simA == -FLT_MAX) ? 0.0f : expf(simA - fmx);
    float eB = (simB == -FLT_MAX) ? 0.0f : expf(simB - fmx);
    float eC = (simC == -FLT_MAX) ? 0.0f : expf(simC - fmx);
    float finv = 1.0f / redsum64(eA + eB + eC);
    float pA = eA * finv, pB = eB * finv, pC = eC * finv;

    // ---- fine PV (rows uniform via sel*, lane = d; only weight shuffles) ----
    const float* vh = vbuf + (size_t)h * 65536 + lane;
    float facc;
    {
        float f0 = 0, f1 = 0, f2 = 0, f3 = 0, f4 = 0;
#pragma unroll
        for (int kk = 0; kk < 32; ++kk) {
            f0 += __shfl(pA, kk)      * vh[(sel0 * 32 + kk) * 64];
            f1 += __shfl(pA, kk + 32) * vh[(sel1 * 32 + kk) * 64];
            f2 += __shfl(pB, kk)      * vh[(sel2 * 32 + kk) * 64];
            f3 += __shfl(pB, kk + 32) * vh[(sel3 * 32 + kk) * 64];
            f4 += __shfl(pC, kk)      * vh[(own * 32 + kk) * 64];
        }
        facc = ((f0 + f1) + (f2 + f3)) + f4;
    }

    // ---- sliding window ----
    const int lo = (s > WIN) ? s - WIN : 0;
    const int cnt = s - lo + 1;          // min(s,64)+1 <= 65
    float sA = bdot(rqv, rkh + (size_t)(lo + lane) * 512) * SCALE;   // rows lo..lo+63 <= 1022
    sA = (lane < cnt) ? sA : -FLT_MAX;
    bool v65 = (s >= 64);                // 65th key exists (row lo+64 = s)
    float s65 = bdot(rqv, rkh + (size_t)(lo + 64) * 512) * SCALE;    // uniform row
    float smx = redmax64(fmaxf(sA, v65 ? s65 : -FLT_MAX));
    float esA = (sA == -FLT_MAX) ? 0.0f : expf(sA - smx);
    float es65 = v65 ? expf(s65 - smx) : 0.0f;   // identical on all lanes
    float ssum = redsum64(esA) + es65;
    float sinv = 1.0f / ssum;
    float psA = esA * sinv;
    float sacc;
    {
        float s0 = 0, s1 = 0, s2 = 0, s3 = 0;
        const float* vlo = vh + (size_t)lo * 64;
#pragma unroll
        for (int kk = 0; kk < 64; kk += 4) {
            s0 += __shfl(psA, kk)     * vlo[(kk + 0) * 64];
            s1 += __shfl(psA, kk + 1) * vlo[(kk + 1) * 64];
            s2 += __shfl(psA, kk + 2) * vlo[(kk + 2) * 64];
            s3 += __shfl(psA, kk + 3) * vlo[(kk + 3) * 64];
        }
        sacc = (s0 + s1) + (s2 + s3) + (es65 * sinv) * vlo[64 * 64];
    }

    // ---- gated combine ----
    const float* st = strat + s * 24 + h * 3;
    att[s * 512 + h * 64 + lane] = st[0] * cacc + st[1] * facc + st[2] * sacc;
}

extern "C" void kernel_launch(void* const* d_in, const int* in_sizes, int n_in,
                              void* d_out, int out_size, void* d_ws, size_t ws_size,
                              hipStream_t stream) {
    const float* inp     = (const float*)d_in[0];
    const float* norm_g  = (const float*)d_in[1];
    const float* w_qkv   = (const float*)d_in[2];
    const float* k_pos   = (const float*)d_in[3];
    const float* v_pos   = (const float*)d_in[4];
    const float* kc_w1   = (const float*)d_in[5];
    const float* kc_b1   = (const float*)d_in[6];
    const float* kc_w2   = (const float*)d_in[7];
    const float* kc_b2   = (const float*)d_in[8];
    const float* vc_w1   = (const float*)d_in[9];
    const float* vc_b1   = (const float*)d_in[10];
    const float* vc_w2   = (const float*)d_in[11];
    const float* vc_b2   = (const float*)d_in[12];
    const float* mem_kv  = (const float*)d_in[13];
    const float* strat_w = (const float*)d_in[14];
    const float* strat_b = (const float*)d_in[15];
    const float* out_w   = (const float*)d_in[16];
    float* out = (float*)d_out;

    float* ws = (float*)d_ws;
    float* x     = ws + OFF_X;
    float* qkv   = ws + OFF_QKV;
    float* rq    = ws + OFF_RQ;
    float* rk    = ws + OFF_RK;
    float* vbuf  = ws + OFF_VBUF;
    float* ckc   = ws + OFF_CKC;
    float* cvc   = ws + OFF_CVC;
    float* strat = ws + OFF_STRAT;
    float* att   = ws + OFF_ATT;
    float* hkv   = ws + OFF_HK;
    float* qkvp  = ws + OFF_QKVP;
    float* compp = ws + OFF_COMPP;
    float* outp  = ws + OFF_OUTP;

    rmsnorm_strat_k<<<1024, 256, 0, stream>>>(inp, norm_g, strat_w, strat_b, x, strat);
    gemm_sk_k<<<dim3(16, 24, 2), 256, 0, stream>>>(x, w_qkv, qkvp, 1024, 1536, 512, 2);
    reduce_qkv_k<<<1536, 256, 0, stream>>>(qkvp, qkv, vbuf);
    rope_apply_k<<<1024, 256, 0, stream>>>(qkv, rq, rk);
    gemm_comp_k<<<dim3(4, 32, 8), 256, 0, stream>>>(qkv, k_pos, v_pos, kc_w1, vc_w1, compp);
    reduce_comp_k<<<1024, 256, 0, stream>>>(compp, kc_b1, vc_b1, hkv);
    gemm_skinny_z2_k<<<dim3(256, 1, 2), 256, 0, stream>>>(hkv, kc_w2, kc_b2, vc_w2, vc_b2, ckc, cvc);
    attn_fused_k<<<dim3(256, 8), 256, 0, stream>>>(qkv, rq, rk, ckc, cvc, mem_kv, vbuf, strat, att);
    gemm_sk_k<<<dim3(16, 8, 4), 256, 0, stream>>>(att, out_w, outp, 1024, 512, 512, 4);
    reduce_k<4><<<512, 256, 0, stream>>>(outp, out, 1024 * 512);
}